// Round 7
// baseline (232.837 us; speedup 1.0000x reference)
//
#include <hip/hip_runtime.h>
#include <hip/hip_bf16.h>

typedef __bf16 bf16;
typedef __attribute__((ext_vector_type(8))) __bf16 bf16x8;
typedef __attribute__((ext_vector_type(4))) __bf16 bf16x4;
typedef __attribute__((ext_vector_type(2))) __bf16 bf16x2;
typedef __attribute__((ext_vector_type(4))) float f32x4;
typedef __attribute__((ext_vector_type(2))) unsigned int u32x2;
typedef __attribute__((ext_vector_type(4))) unsigned int u32x4;

#define MFMA16(a, b, c) __builtin_amdgcn_mfma_f32_16x16x32_bf16((a), (b), (c), 0, 0, 0)
#define SM_SCALE 0.18033688011112043f  // (1/8) * log2(e), folded into q at GEMM epilogue

__device__ __forceinline__ void gld_lds16(const bf16* g, bf16* l) {
    __builtin_amdgcn_global_load_lds((const __attribute__((address_space(1))) void*)g,
                                     (__attribute__((address_space(3))) void*)l, 16, 0, 0);
}

// raw barriers: no compiler-inserted vmcnt(0)/lgkmcnt(0) drain at each barrier.
#define PBAR() asm volatile("s_barrier" ::: "memory")
#define VWAIT0() asm volatile("s_waitcnt vmcnt(0)" ::: "memory")
#define VWAIT2() asm volatile("s_waitcnt vmcnt(2)" ::: "memory")
#define VWAIT3() asm volatile("s_waitcnt vmcnt(3)" ::: "memory")
#define VWAIT4() asm volatile("s_waitcnt vmcnt(4)" ::: "memory")

// ---------------- prep: W transpose (blocks 0..767) + x f32->bf16 (blocks 768..2815) --------
__global__ __launch_bounds__(256) void prep(const float* __restrict__ W0,
                                            const float* __restrict__ W1,
                                            const float* __restrict__ W2,
                                            bf16* __restrict__ Wt,
                                            const float* __restrict__ xin,
                                            bf16* __restrict__ xout) {
    __shared__ float tile[64][65];
    const int blk = blockIdx.x;
    const int tid = threadIdx.x;
    if (blk < 768) {
        const int z = blk >> 8, rem = blk & 255;
        const int r0 = (rem >> 4) * 64;  // k
        const int c0 = (rem & 15) * 64;  // n
        const float* W = (z == 0) ? W0 : ((z == 1) ? W1 : W2);
        bf16* dst = Wt + (size_t)z * 1024 * 1024;
        for (int i = tid; i < 4096; i += 256) {
            int r = i >> 6, cc = i & 63;
            tile[r][cc] = W[(size_t)(r0 + r) * 1024 + c0 + cc];
        }
        __syncthreads();
        for (int i = tid; i < 4096; i += 256) {
            int n = i >> 6, k = i & 63;
            dst[(size_t)(c0 + n) * 1024 + r0 + k] = (bf16)tile[k][n];
        }
    } else {
        // 2048 blocks x 256 threads x 16 floats = 8,388,608 = 8192*1024 exactly
        const size_t i0 = ((size_t)(blk - 768) * 256 + tid) * 16;
#pragma unroll
        for (int j = 0; j < 2; j++) {
            const float4 v0 = *(const float4*)(xin + i0 + j * 8);
            const float4 v1 = *(const float4*)(xin + i0 + j * 8 + 4);
            bf16x8 o = {(bf16)v0.x, (bf16)v0.y, (bf16)v0.z, (bf16)v0.w,
                        (bf16)v1.x, (bf16)v1.y, (bf16)v1.z, (bf16)v1.w};
            *(bf16x8*)(xout + i0 + j * 8) = o;
        }
    }
}

// ---------------- GEMM: BMx128 tile, BK=32, 8 waves, 3-buf depth-2 ----------------
// R13 vs R11: (1) swizzle uses l16 bits 1-2 -- chunk = quad ^ ((l16>>1)&3) -- so within
// each 16-lane ds_read phase only pairs {l16,l16+8} share a bank (2-way = free, m136);
// the old quad^(l16&3) left 4-way groups {l16,l16+4,+8,+12} = the 6.29M conflict cycles.
// Stage-source pre-swizzle uses the same involution (rule #21). (2) MODE 1 (proj) now
// BM=128: grid 512 = exactly 2 blocks/CU (balanced, was 256 = 1/CU).
// MODE 0: fused QKV (N=3072; q pre-scaled, v transposed into Vt). MODE 1: f32 out, N=1024.
template <int MODE>
__global__ __launch_bounds__(512, 4) void gemm_main(const bf16* __restrict__ A,
                                                    const bf16* __restrict__ Bt,
                                                    const float* __restrict__ b0,
                                                    const float* __restrict__ b1,
                                                    const float* __restrict__ b2,
                                                    void* __restrict__ out0,
                                                    void* __restrict__ out1,
                                                    void* __restrict__ out2,
                                                    int nbx) {
    constexpr int BM = (MODE == 0) ? 256 : 128;
    constexpr int WN = (MODE == 0) ? 2 : 4;     // wave grid (8/WN) x WN
    constexpr int WCOLS = 128 / WN;             // per-wave N span: 64 or 32
    constexpr int NR = WCOLS / 16;              // N fragments: 4 or 2
    constexpr int BUFSZ = (BM + 128) * 32;      // elements per buffer

    __shared__ alignas(16) bf16 LDS[3 * BUFSZ];

    // XCD-chunked bijective swizzle (grid % 8 == 0): contiguous work chunk per XCD.
    const int orig = blockIdx.x;
    const int chunk = (int)gridDim.x >> 3;
    const int swz = (orig & 7) * chunk + (orig >> 3);
    const int by = swz / nbx, bx = swz % nbx;
    const int m0 = by * BM, n0 = bx * 128;

    const int tid = threadIdx.x;
    const int wid = tid >> 6, lane = tid & 63;
    const int wr = wid / WN, wc = wid % WN;
    const int quad = lane >> 4, l16 = lane & 15;

    // staging: thread t covers A row (t>>2) [+128 if BM=256] and B row (t>>2), 16B chunk
    // (t&3); source chunk pre-swizzled by ((row>>1)&3) so linear LDS + XOR read matches.
    const int sr = tid >> 2;
    const int scol = (((tid & 3) ^ ((sr >> 1) & 3)) * 8);
    const bf16* gA = A + (size_t)(m0 + sr) * 1024 + scol;
    const bf16* gB = Bt + (size_t)(n0 + sr) * 1024 + scol;
    bf16* lA = &LDS[tid * 8];
    bf16* lB = &LDS[BM * 32 + tid * 8];

    // read-side swizzled chunk: (row>>1)&3 == (l16>>1)&3 for all fragment rows
    const int coff = ((quad ^ ((l16 >> 1) & 3)) * 8);

    f32x4 acc[4][NR] = {};

    auto STAGE = [&](int kt, int p) {
        const int base = p * BUFSZ;
        gld_lds16(gA + kt * 32, lA + base);
        if constexpr (BM == 256)
            gld_lds16(gA + kt * 32 + (size_t)128 * 1024, lA + base + 4096);
        gld_lds16(gB + kt * 32, lB + base);
    };

    STAGE(0, 0);
    STAGE(1, 1);
    if constexpr (BM == 256) VWAIT3(); else VWAIT2();  // drain stage(0), keep stage(1) in flight
    PBAR();

    int rb = 0;   // read buffer for kt
    int sb = 2;   // stage buffer for kt+2
#pragma unroll 1
    for (int kt = 0; kt < 32; kt++) {
        const bf16* Asp = &LDS[rb * BUFSZ];
        const bf16* Bsp = Asp + BM * 32;
        if (kt + 2 < 32) STAGE(kt + 2, sb);  // buf freed at kt-1's closing barrier

        bf16x8 af[4], bfr[NR];
#pragma unroll
        for (int m4 = 0; m4 < 4; m4++)
            af[m4] = *(const bf16x8*)&Asp[(wr * 64 + m4 * 16 + l16) * 32 + coff];
#pragma unroll
        for (int ni = 0; ni < NR; ni++)
            bfr[ni] = *(const bf16x8*)&Bsp[(wc * WCOLS + ni * 16 + l16) * 32 + coff];

        __builtin_amdgcn_s_setprio(1);
#pragma unroll
        for (int m4 = 0; m4 < 4; m4++)
#pragma unroll
            for (int ni = 0; ni < NR; ni++)
                acc[m4][ni] = MFMA16(af[m4], bfr[ni], acc[m4][ni]);
        __builtin_amdgcn_s_setprio(0);

        if (kt < 30) {
            if constexpr (BM == 256) VWAIT3(); else VWAIT2();  // drain stage(kt+1) only
            PBAR();
        } else if (kt == 30) {
            VWAIT0();  // last outstanding: STAGE(31)
            PBAR();
        }
        rb = (rb == 2) ? 0 : rb + 1;
        sb = (sb == 2) ? 0 : sb + 1;
    }

    // epilogue
    const int nl0 = (n0 & 1023) + wc * WCOLS;
    const int mb0 = m0 + wr * 64;
    if (MODE == 0) {
        const int sel = n0 >> 10;  // 0=q, 1=k, 2=v  (128 | 1024 -> never straddles)
        if (sel < 2) {
            const float* bias = (sel == 0) ? b0 : b1;
            bf16* Cp = (bf16*)((sel == 0) ? out0 : out1);
            const float qs = (sel == 0) ? SM_SCALE : 1.0f;
#pragma unroll
            for (int mi = 0; mi < 4; mi++) {
                const int mbase = mb0 + mi * 16 + quad * 4;
#pragma unroll
                for (int ni = 0; ni < NR; ni++) {
                    const int nl = nl0 + ni * 16 + l16;
                    const float bv = bias[nl];
#pragma unroll
                    for (int r = 0; r < 4; r++)
                        Cp[(size_t)(mbase + r) * 1024 + nl] =
                            (bf16)((acc[mi][ni][r] + bv) * qs);
                }
            }
        } else {
            bf16* Vt = (bf16*)out2;
            const int b = m0 >> 11;  // 2048 rows/batch; BM-row block never straddles
#pragma unroll
            for (int ni = 0; ni < NR; ni++) {
                const int nl = nl0 + ni * 16 + l16;
                const int h = nl >> 6, d = nl & 63;
                const float bv = b2[nl];
                bf16* dst = Vt + ((size_t)(b * 16 + h) * 64 + d) * 2048;
#pragma unroll
                for (int mi = 0; mi < 4; mi++) {
                    const int t0 = (mb0 + mi * 16 + quad * 4) & 2047;  // batch-local t
                    bf16x4 w = {(bf16)(acc[mi][ni][0] + bv), (bf16)(acc[mi][ni][1] + bv),
                                (bf16)(acc[mi][ni][2] + bv), (bf16)(acc[mi][ni][3] + bv)};
                    *(bf16x4*)&dst[t0] = w;
                }
            }
        }
    } else {
        float* Cp = (float*)out0;
#pragma unroll
        for (int mi = 0; mi < 4; mi++) {
            const int mbase = mb0 + mi * 16 + quad * 4;
#pragma unroll
            for (int ni = 0; ni < NR; ni++) {
                const int n = n0 + wc * WCOLS + ni * 16 + l16;
                const float bv = b0[n];
#pragma unroll
                for (int r = 0; r < 4; r++)
                    Cp[(size_t)(mbase + r) * 1024 + n] = acc[mi][ni][r] + bv;
            }
        }
    }
}

// ---------------- flash attention, causal, hs=64 (R12 structure, unchanged) ----------------
template <bool NEEDMASK>
__device__ __forceinline__ void softmax_reg(const f32x4* st, bf16x8* pf, int qrel) {
    unsigned int p[4][2];
#pragma unroll
    for (int j = 0; j < 4; j++) {
        float pv[4];
#pragma unroll
        for (int r = 0; r < 4; r++) {
            float s = st[j][r];
            if (NEEDMASK && (j * 16 + r > qrel)) s = -1e30f;
            pv[r] = __builtin_amdgcn_exp2f(s);
        }
        bf16x2 w0 = {(bf16)pv[0], (bf16)pv[1]};  // v_cvt_pk_bf16_f32 (compiler-fused)
        bf16x2 w1 = {(bf16)pv[2], (bf16)pv[3]};
        p[j][0] = __builtin_bit_cast(unsigned int, w0);
        p[j][1] = __builtin_bit_cast(unsigned int, w1);
    }
    // acc layout -> B-frag layout: permlane32_swap then permlane16_swap (l16 invariant)
#pragma unroll
    for (int ks = 0; ks < 2; ks++) {
        unsigned int q4[4];
#pragma unroll
        for (int h = 0; h < 2; h++) {
            u32x2 s32 = __builtin_amdgcn_permlane32_swap(p[2 * ks][h], p[2 * ks + 1][h],
                                                         false, false);
            u32x2 s16 = __builtin_amdgcn_permlane16_swap(s32[0], s32[1], false, false);
            q4[h] = s16[0];      // e2 = h     (kv ofs 2h, 2h+1)
            q4[2 + h] = s16[1];  // e2 = 2+h   (kv ofs 4+2h, 5+2h)
        }
        u32x4 qq = {q4[0], q4[1], q4[2], q4[3]};
        pf[ks] = __builtin_bit_cast(bf16x8, qq);
    }
}

__global__ __launch_bounds__(256, 3) void attn(const bf16* __restrict__ Q,
                                               const bf16* __restrict__ Kg,
                                               const bf16* __restrict__ Vt,
                                               bf16* __restrict__ O) {
    // bijective XCD swizzle: all 16 j-blocks of a (b,h) on one XCD (8 bh/XCD).
    const int lin = blockIdx.y * 16 + blockIdx.x;
    const int bh = (lin & 7) * 8 + ((lin >> 3) & 7);
    const int jb = lin >> 6;  // [0,16)
    const int b = bh >> 4, h = bh & 15;
    const int tid = threadIdx.x;
    const int wave = tid >> 6, lane = tid & 63;
    const int quad = lane >> 4, l16 = lane & 15;

    __shared__ alignas(16) bf16 KVs[3 * 8192];  // 3-buf; per buf: K 64x64 | V^T 64x64 (swz)

    const bf16* Kbase = Kg + ((size_t)b * 2048) * 1024 + h * 64;
    const bf16* Vbase = Vt + (size_t)bh * 64 * 2048;

    const int srow = tid >> 3;
    const int schunk = (tid & 7) ^ (srow & 7);

    const int xorE = (l16 & 7) * 8;
    const int cofA = (quad * 8) ^ xorE;       // ks=0
    const int cofB = (32 + quad * 8) ^ xorE;  // ks=1

    const bf16 one1 = (bf16)1.0f;
    const bf16x8 onesf = {one1, one1, one1, one1, one1, one1, one1, one1};

#pragma unroll 1
    for (int phase = 0; phase < 2; phase++) {
        const int qs = (phase == 0) ? (31 - jb) : jb;
        const int q0 = qs * 64;
        const bf16* Qbase = Q + ((size_t)(b * 2048 + q0)) * 1024 + h * 64;

        bf16x8 qf[2];
#pragma unroll
        for (int ks = 0; ks < 2; ks++)
            qf[ks] = *(const bf16x8*)&Qbase[(size_t)(wave * 16 + l16) * 1024 + ks * 32 + quad * 8];

        f32x4 ot[4] = {};
        f32x4 lacc = {0.f, 0.f, 0.f, 0.f};
        const int ntiles = qs + 1;
        const int qrel = wave * 16 + l16 - quad * 4;

        const bf16* pK = Kbase + (size_t)srow * 1024 + schunk * 8;
        const bf16* pK2 = pK + (size_t)32 * 1024;
        const bf16* pV = Vbase + (size_t)srow * 2048 + schunk * 8;
        const bf16* pV2 = pV + (size_t)32 * 2048;

        // prologue: stage tiles 0 and 1 (tile 1 rows always in-bounds; unused if ntiles==1)
        {
            bf16* nb = &KVs[tid * 8];
            gld_lds16(pK, nb);
            gld_lds16(pK2, nb + 2048);
            gld_lds16(pV, nb + 4096);
            gld_lds16(pV2, nb + 6144);
            pK += 64 * 1024; pK2 += 64 * 1024; pV += 64; pV2 += 64;
            nb = &KVs[8192 + tid * 8];
            gld_lds16(pK, nb);
            gld_lds16(pK2, nb + 2048);
            gld_lds16(pV, nb + 4096);
            gld_lds16(pV2, nb + 6144);
            pK += 64 * 1024; pK2 += 64 * 1024; pV += 64; pV2 += 64;
        }
        VWAIT4();  // drain stage(0); stage(1) stays in flight
        PBAR();

        int rbuf = 0, sbuf = 2;
#pragma unroll 1
        for (int tk = 0; tk < ntiles; tk++) {
            const bf16* buf = &KVs[rbuf * 8192];
            if (tk + 2 < ntiles) {  // stage(t+2): drained at t+1's end (2 bodies away)
                bf16* nb = &KVs[sbuf * 8192 + tid * 8];
                gld_lds16(pK, nb);
                gld_lds16(pK2, nb + 2048);
                gld_lds16(pV, nb + 4096);
                gld_lds16(pV2, nb + 6144);
                pK += 64 * 1024; pK2 += 64 * 1024; pV += 64; pV2 += 64;
            }

            // S^T = K . Q^T
            f32x4 st[4] = {};
#pragma unroll
            for (int ks = 0; ks < 2; ks++)
#pragma unroll
                for (int j = 0; j < 4; j++) {
                    const bf16x8 kf =
                        *(const bf16x8*)&buf[(j * 16 + l16) * 64 + (ks ? cofB : cofA)];
                    st[j] = MFMA16(kf, qf[ks], st[j]);
                }

            // softmax + in-register P redistribution
            bf16x8 pf[2];
            if (tk == ntiles - 1)
                softmax_reg<true>(st, pf, qrel);
            else
                softmax_reg<false>(st, pf, qrel);

            // l-sum via MFMA ones-fragment
            lacc = MFMA16(onesf, pf[0], lacc);
            lacc = MFMA16(onesf, pf[1], lacc);

            // O^T += V^T . P^T
#pragma unroll
            for (int ks = 0; ks < 2; ks++)
#pragma unroll
                for (int db = 0; db < 4; db++) {
                    const bf16x8 vf = *(const bf16x8*)&buf[4096 + (db * 16 + l16) * 64 +
                                                           (ks ? cofB : cofA)];
                    ot[db] = MFMA16(vf, pf[ks], ot[db]);
                }

            if (tk + 1 < ntiles) {
                if (tk + 2 < ntiles) VWAIT4();  // drain stage(t+1); stage(t+2) in flight
                else VWAIT0();                  // tail: drain the last stage
                PBAR();                         // publish t+1; buf[rbuf] readers done
            }
            rbuf = (rbuf == 2) ? 0 : rbuf + 1;
            sbuf = (sbuf == 2) ? 0 : sbuf + 1;
        }

        // epilogue: O^T regs -> transpose staging in buf[(ntiles+1)%3] (idle: its last
        // readers finished at tile ntiles-2's barrier; never a pending gld_lds target).
        const float inv = 1.f / lacc[0];
        bf16* ep = &KVs[((ntiles + 1) % 3) * 8192 + wave * (16 * 72)];
#pragma unroll
        for (int db = 0; db < 4; db++) {
            bf16x4 w = {(bf16)(ot[db][0] * inv), (bf16)(ot[db][1] * inv),
                        (bf16)(ot[db][2] * inv), (bf16)(ot[db][3] * inv)};
            *(bf16x4*)&ep[l16 * 72 + db * 16 + quad * 4] = w;
        }
        {
            const int orow = lane >> 2, oc = (lane & 3) * 16;
            bf16* Obase =
                O + ((size_t)(b * 2048 + q0 + wave * 16 + orow)) * 1024 + h * 64 + oc;
            const bf16* src = &ep[orow * 72 + oc];
            *(bf16x8*)&Obase[0] = *(const bf16x8*)&src[0];
            *(bf16x8*)&Obase[8] = *(const bf16x8*)&src[8];
        }
        __syncthreads();  // full drain (incl. stray ntiles==1 stage) + epilogue reads done
    }
}

extern "C" void kernel_launch(void* const* d_in, const int* in_sizes, int n_in,
                              void* d_out, int out_size, void* d_ws, size_t ws_size,
                              hipStream_t stream) {
    const float* x = (const float*)d_in[0];
    const float* Wq = (const float*)d_in[1];
    const float* bq = (const float*)d_in[2];
    const float* Wk = (const float*)d_in[3];
    const float* bk = (const float*)d_in[4];
    const float* Wv = (const float*)d_in[5];
    const float* bv = (const float*)d_in[6];
    float* out = (float*)d_out;

    const int M = 8192;  // B*T
    const size_t sz_x = (size_t)M * 1024;
    const size_t sz_w = (size_t)1024 * 1024;

    char* p = (char*)d_ws;
    bf16* xb = (bf16*)p;   p += sz_x * 2;
    bf16* Wcat = (bf16*)p; p += 3 * sz_w * 2;  // [Wq^T ; Wk^T ; Wv^T]
    bf16* qb = (bf16*)p;   p += sz_x * 2;
    bf16* kb = (bf16*)p;   p += sz_x * 2;
    bf16* Vt = (bf16*)p;   p += sz_x * 2;  // [B*H][64][2048]
    bf16* yatt = (bf16*)p; p += sz_x * 2;

    // W transpose + x convert in one launch
    prep<<<dim3(2816), dim3(256), 0, stream>>>(Wq, Wk, Wv, Wcat, x, xb);

    // fused QKV projection: [8192,1024] @ [1024,3072] -- 256x128/BK32, 3-buf depth-2
    gemm_main<0><<<dim3(768), dim3(512), 0, stream>>>(xb, Wcat, bq, bk, bv, qb, kb, Vt, 24);
    attn<<<dim3(16, 64), dim3(256), 0, stream>>>(qb, kb, Vt, yatt);
    // output projection (reference reuses v_proj): 128x128 tile, grid 512 = 2/CU balanced
    gemm_main<1><<<dim3(512), dim3(512), 0, stream>>>(yatt, Wcat + 2 * sz_w, bv, bv, bv,
                                                      out, out, out, 8);
}

// Round 8
// 228.105 us; speedup vs baseline: 1.0207x; 1.0207x over previous
//
#include <hip/hip_runtime.h>
#include <hip/hip_bf16.h>

typedef __bf16 bf16;
typedef __attribute__((ext_vector_type(8))) __bf16 bf16x8;
typedef __attribute__((ext_vector_type(4))) __bf16 bf16x4;
typedef __attribute__((ext_vector_type(2))) __bf16 bf16x2;
typedef __attribute__((ext_vector_type(4))) float f32x4;
typedef __attribute__((ext_vector_type(2))) unsigned int u32x2;
typedef __attribute__((ext_vector_type(4))) unsigned int u32x4;

#define MFMA16(a, b, c) __builtin_amdgcn_mfma_f32_16x16x32_bf16((a), (b), (c), 0, 0, 0)
#define SM_SCALE 0.18033688011112043f  // (1/8) * log2(e), folded into q at GEMM epilogue

__device__ __forceinline__ void gld_lds16(const bf16* g, bf16* l) {
    __builtin_amdgcn_global_load_lds((const __attribute__((address_space(1))) void*)g,
                                     (__attribute__((address_space(3))) void*)l, 16, 0, 0);
}

// raw barriers: no compiler-inserted vmcnt(0)/lgkmcnt(0) drain at each barrier.
#define PBAR() asm volatile("s_barrier" ::: "memory")
#define VWAIT0() asm volatile("s_waitcnt vmcnt(0)" ::: "memory")
#define VWAIT3() asm volatile("s_waitcnt vmcnt(3)" ::: "memory")
#define VWAIT4() asm volatile("s_waitcnt vmcnt(4)" ::: "memory")

// ---------------- prep: W transpose (blocks 0..767) + x f32->bf16 (blocks 768..2815) --------
__global__ __launch_bounds__(256) void prep(const float* __restrict__ W0,
                                            const float* __restrict__ W1,
                                            const float* __restrict__ W2,
                                            bf16* __restrict__ Wt,
                                            const float* __restrict__ xin,
                                            bf16* __restrict__ xout) {
    __shared__ float tile[64][65];
    const int blk = blockIdx.x;
    const int tid = threadIdx.x;
    if (blk < 768) {
        const int z = blk >> 8, rem = blk & 255;
        const int r0 = (rem >> 4) * 64;  // k
        const int c0 = (rem & 15) * 64;  // n
        const float* W = (z == 0) ? W0 : ((z == 1) ? W1 : W2);
        bf16* dst = Wt + (size_t)z * 1024 * 1024;
        for (int i = tid; i < 4096; i += 256) {
            int r = i >> 6, cc = i & 63;
            tile[r][cc] = W[(size_t)(r0 + r) * 1024 + c0 + cc];
        }
        __syncthreads();
        for (int i = tid; i < 4096; i += 256) {
            int n = i >> 6, k = i & 63;
            dst[(size_t)(c0 + n) * 1024 + r0 + k] = (bf16)tile[k][n];
        }
    } else {
        // 2048 blocks x 256 threads x 16 floats = 8,388,608 = 8192*1024 exactly
        const size_t i0 = ((size_t)(blk - 768) * 256 + tid) * 16;
#pragma unroll
        for (int j = 0; j < 2; j++) {
            const float4 v0 = *(const float4*)(xin + i0 + j * 8);
            const float4 v1 = *(const float4*)(xin + i0 + j * 8 + 4);
            bf16x8 o = {(bf16)v0.x, (bf16)v0.y, (bf16)v0.z, (bf16)v0.w,
                        (bf16)v1.x, (bf16)v1.y, (bf16)v1.z, (bf16)v1.w};
            *(bf16x8*)(xout + i0 + j * 8) = o;
        }
    }
}

// ---------------- GEMM: 256x128 tile, BK=32, 8 waves (4Mx2N), 64x64/wave, 3-buf ----------------
// R14 = R13 pipeline + conflict-free swizzle, with MODE-1 proj geometry REVERTED to
// BM=256/grid-256 (R7's 128^2 proj regressed ~7us). MODE differs only in the epilogue.
template <int MODE>
__global__ __launch_bounds__(512, 4) void gemm_main(const bf16* __restrict__ A,
                                                    const bf16* __restrict__ Bt,
                                                    const float* __restrict__ b0,
                                                    const float* __restrict__ b1,
                                                    const float* __restrict__ b2,
                                                    void* __restrict__ out0,
                                                    void* __restrict__ out1,
                                                    void* __restrict__ out2,
                                                    int nbx) {
    __shared__ alignas(16) bf16 LDS[3 * 12288];  // per buf: A 256x32 @0 | B 128x32 @8192

    // XCD-chunked bijective swizzle (grid % 8 == 0): contiguous work chunk per XCD.
    const int orig = blockIdx.x;
    const int chunk = (int)gridDim.x >> 3;
    const int swz = (orig & 7) * chunk + (orig >> 3);
    const int by = swz / nbx, bx = swz % nbx;
    const int m0 = by * 256, n0 = bx * 128;

    const int tid = threadIdx.x;
    const int wid = tid >> 6, lane = tid & 63;
    const int wr = wid >> 1, wc = wid & 1;  // wave grid 4M x 2N; per-wave out 64x64
    const int quad = lane >> 4, l16 = lane & 15;

    // staging: thread t covers A rows (t>>2, 128+(t>>2)) and B row (t>>2), 16B chunk
    // (t&3); source chunk pre-swizzled by ((row>>1)&3) so linear LDS + XOR read matches
    // (2-way-only bank aliasing within each 16-lane ds_read phase -> 0 conflicts, R7).
    const int sr = tid >> 2;
    const int scol = (((tid & 3) ^ ((sr >> 1) & 3)) * 8);
    const bf16* gA = A + (size_t)(m0 + sr) * 1024 + scol;
    const bf16* gB = Bt + (size_t)(n0 + sr) * 1024 + scol;
    bf16* lA = &LDS[tid * 8];
    bf16* lB = &LDS[8192 + tid * 8];

    // read-side swizzled chunk: (row>>1)&3 == (l16>>1)&3 for all fragment rows
    const int coff = ((quad ^ ((l16 >> 1) & 3)) * 8);

    f32x4 acc[4][4] = {};

    auto STAGE = [&](int kt, int p) {
        const int base = p * 12288;
        gld_lds16(gA + kt * 32, lA + base);
        gld_lds16(gA + kt * 32 + (size_t)128 * 1024, lA + base + 4096);
        gld_lds16(gB + kt * 32, lB + base);
    };

    STAGE(0, 0);
    STAGE(1, 1);
    VWAIT3();  // drain STAGE(0); STAGE(1) stays in flight
    PBAR();

    int rb = 0;   // read buffer for kt
    int sb = 2;   // stage buffer for kt+2
#pragma unroll 1
    for (int kt = 0; kt < 32; kt++) {
        const bf16* Asp = &LDS[rb * 12288];
        const bf16* Bsp = Asp + 8192;
        if (kt + 2 < 32) STAGE(kt + 2, sb);  // buf freed at kt-1's closing barrier

        bf16x8 af[4], bfr[4];
#pragma unroll
        for (int m4 = 0; m4 < 4; m4++)
            af[m4] = *(const bf16x8*)&Asp[(wr * 64 + m4 * 16 + l16) * 32 + coff];
#pragma unroll
        for (int ni = 0; ni < 4; ni++)
            bfr[ni] = *(const bf16x8*)&Bsp[(wc * 64 + ni * 16 + l16) * 32 + coff];

        __builtin_amdgcn_s_setprio(1);
#pragma unroll
        for (int m4 = 0; m4 < 4; m4++)
#pragma unroll
            for (int ni = 0; ni < 4; ni++)
                acc[m4][ni] = MFMA16(af[m4], bfr[ni], acc[m4][ni]);
        __builtin_amdgcn_s_setprio(0);

        if (kt < 30) {
            VWAIT3();  // drain stage(kt+1) only; stage(kt+2) flies across the barrier
            PBAR();
        } else if (kt == 30) {
            VWAIT0();  // last outstanding: STAGE(31)
            PBAR();
        }
        rb = (rb == 2) ? 0 : rb + 1;
        sb = (sb == 2) ? 0 : sb + 1;
    }

    // epilogue
    const int nl0 = (n0 & 1023) + wc * 64;
    const int mb0 = m0 + wr * 64;
    if (MODE == 0) {
        const int sel = n0 >> 10;  // 0=q, 1=k, 2=v  (128 | 1024 -> never straddles)
        if (sel < 2) {
            const float* bias = (sel == 0) ? b0 : b1;
            bf16* Cp = (bf16*)((sel == 0) ? out0 : out1);
            const float qs = (sel == 0) ? SM_SCALE : 1.0f;
#pragma unroll
            for (int mi = 0; mi < 4; mi++) {
                const int mbase = mb0 + mi * 16 + quad * 4;
#pragma unroll
                for (int ni = 0; ni < 4; ni++) {
                    const int nl = nl0 + ni * 16 + l16;
                    const float bv = bias[nl];
#pragma unroll
                    for (int r = 0; r < 4; r++)
                        Cp[(size_t)(mbase + r) * 1024 + nl] =
                            (bf16)((acc[mi][ni][r] + bv) * qs);
                }
            }
        } else {
            bf16* Vt = (bf16*)out2;
            const int b = m0 >> 11;  // 2048 rows/batch; 256-row block never straddles
#pragma unroll
            for (int ni = 0; ni < 4; ni++) {
                const int nl = nl0 + ni * 16 + l16;
                const int h = nl >> 6, d = nl & 63;
                const float bv = b2[nl];
                bf16* dst = Vt + ((size_t)(b * 16 + h) * 64 + d) * 2048;
#pragma unroll
                for (int mi = 0; mi < 4; mi++) {
                    const int t0 = (mb0 + mi * 16 + quad * 4) & 2047;  // batch-local t
                    bf16x4 w = {(bf16)(acc[mi][ni][0] + bv), (bf16)(acc[mi][ni][1] + bv),
                                (bf16)(acc[mi][ni][2] + bv), (bf16)(acc[mi][ni][3] + bv)};
                    *(bf16x4*)&dst[t0] = w;
                }
            }
        }
    } else {
        float* Cp = (float*)out0;
#pragma unroll
        for (int mi = 0; mi < 4; mi++) {
            const int mbase = mb0 + mi * 16 + quad * 4;
#pragma unroll
            for (int ni = 0; ni < 4; ni++) {
                const int n = n0 + wc * 64 + ni * 16 + l16;
                const float bv = b0[n];
#pragma unroll
                for (int r = 0; r < 4; r++)
                    Cp[(size_t)(mbase + r) * 1024 + n] = acc[mi][ni][r] + bv;
            }
        }
    }
}

// ---------------- flash attention, causal, hs=64 ----------------
// R15 vs R12: 2 q-strips per wave (block owns 128 q-rows). Every kf/vf LDS read now
// feeds TWO MFMAs (one per strip) -> LDS-read bytes per FLOP halve (attn was LDS-pipe
// bound: 2.2GB reads / 52TB/s = 42us floor; now ~1.2GB). K/V staging traffic also
// halves (each tile serves 128 q). Grid 512 = exactly 2 blocks/CU, all resident, no
// tail. Strip pairing js = 15-jb (phase 0) / jb (phase 1) -> uniform 36 tiles/block.
// Masking: tile 2js = strip A diagonal (qrel); tile 2js+1 = strip B diagonal (qrel),
// strip A fully masked (qrel-64 -> all-masked -> pfA=0, contributes nothing).
// Same 3-buf depth-2 counted-vmcnt pipeline, same swizzles, same MFMA l-sum.
template <bool NEEDMASK>
__device__ __forceinline__ void softmax_reg(const f32x4* st, bf16x8* pf, int qrel) {
    unsigned int p[4][2];
#pragma unroll
    for (int j = 0; j < 4; j++) {
        float pv[4];
#pragma unroll
        for (int r = 0; r < 4; r++) {
            float s = st[j][r];
            if (NEEDMASK && (j * 16 + r > qrel)) s = -1e30f;
            pv[r] = __builtin_amdgcn_exp2f(s);
        }
        bf16x2 w0 = {(bf16)pv[0], (bf16)pv[1]};  // v_cvt_pk_bf16_f32 (compiler-fused)
        bf16x2 w1 = {(bf16)pv[2], (bf16)pv[3]};
        p[j][0] = __builtin_bit_cast(unsigned int, w0);
        p[j][1] = __builtin_bit_cast(unsigned int, w1);
    }
    // acc layout -> B-frag layout: permlane32_swap then permlane16_swap (l16 invariant)
#pragma unroll
    for (int ks = 0; ks < 2; ks++) {
        unsigned int q4[4];
#pragma unroll
        for (int h = 0; h < 2; h++) {
            u32x2 s32 = __builtin_amdgcn_permlane32_swap(p[2 * ks][h], p[2 * ks + 1][h],
                                                         false, false);
            u32x2 s16 = __builtin_amdgcn_permlane16_swap(s32[0], s32[1], false, false);
            q4[h] = s16[0];      // e2 = h     (kv ofs 2h, 2h+1)
            q4[2 + h] = s16[1];  // e2 = 2+h   (kv ofs 4+2h, 5+2h)
        }
        u32x4 qq = {q4[0], q4[1], q4[2], q4[3]};
        pf[ks] = __builtin_bit_cast(bf16x8, qq);
    }
}

__global__ __launch_bounds__(256, 2) void attn(const bf16* __restrict__ Q,
                                               const bf16* __restrict__ Kg,
                                               const bf16* __restrict__ Vt,
                                               bf16* __restrict__ O) {
    // bijective XCD swizzle: 512 blocks; lin%8 = XCD -> 8 whole (b,h) heads per XCD.
    const int lin = blockIdx.x;
    const int bh = (lin & 7) * 8 + ((lin >> 3) & 7);
    const int jb = lin >> 6;  // [0,8)
    const int b = bh >> 4, h = bh & 15;
    const int tid = threadIdx.x;
    const int wave = tid >> 6, lane = tid & 63;
    const int quad = lane >> 4, l16 = lane & 15;

    __shared__ alignas(16) bf16 KVs[3 * 8192];  // 3-buf; per buf: K 64x64 | V^T 64x64 (swz)

    const bf16* Kbase = Kg + ((size_t)b * 2048) * 1024 + h * 64;
    const bf16* Vbase = Vt + (size_t)bh * 64 * 2048;

    const int srow = tid >> 3;
    const int schunk = (tid & 7) ^ (srow & 7);

    const int xorE = (l16 & 7) * 8;
    const int cofA = (quad * 8) ^ xorE;       // ks=0
    const int cofB = (32 + quad * 8) ^ xorE;  // ks=1

    const bf16 one1 = (bf16)1.0f;
    const bf16x8 onesf = {one1, one1, one1, one1, one1, one1, one1, one1};

#pragma unroll 1
    for (int phase = 0; phase < 2; phase++) {
        // strip pairing at 128-q granularity: (15-jb) then jb -> 36 tiles total
        const int js = (phase == 0) ? (15 - jb) : jb;
        const int q0 = js * 128;
        const bf16* Qbase = Q + ((size_t)(b * 2048 + q0)) * 1024 + h * 64;

        // Q fragments for both strips (A: rows 0-63, B: rows 64-127 of the q-block)
        bf16x8 qfA[2], qfB[2];
#pragma unroll
        for (int ks = 0; ks < 2; ks++) {
            qfA[ks] = *(const bf16x8*)&Qbase[(size_t)(wave * 16 + l16) * 1024 + ks * 32 + quad * 8];
            qfB[ks] = *(const bf16x8*)&Qbase[(size_t)(64 + wave * 16 + l16) * 1024 + ks * 32 + quad * 8];
        }

        f32x4 otA[4] = {}, otB[4] = {};
        f32x4 laccA = {0.f, 0.f, 0.f, 0.f}, laccB = {0.f, 0.f, 0.f, 0.f};
        const int ntiles = 2 * js + 2;
        const int qrel = wave * 16 + l16 - quad * 4;

        const bf16* pK = Kbase + (size_t)srow * 1024 + schunk * 8;
        const bf16* pK2 = pK + (size_t)32 * 1024;
        const bf16* pV = Vbase + (size_t)srow * 2048 + schunk * 8;
        const bf16* pV2 = pV + (size_t)32 * 2048;

        // prologue: stage tiles 0 and 1 (ntiles >= 2 always)
        {
            bf16* nb = &KVs[tid * 8];
            gld_lds16(pK, nb);
            gld_lds16(pK2, nb + 2048);
            gld_lds16(pV, nb + 4096);
            gld_lds16(pV2, nb + 6144);
            pK += 64 * 1024; pK2 += 64 * 1024; pV += 64; pV2 += 64;
            nb = &KVs[8192 + tid * 8];
            gld_lds16(pK, nb);
            gld_lds16(pK2, nb + 2048);
            gld_lds16(pV, nb + 4096);
            gld_lds16(pV2, nb + 6144);
            pK += 64 * 1024; pK2 += 64 * 1024; pV += 64; pV2 += 64;
        }
        VWAIT4();  // drain stage(0); stage(1) stays in flight
        PBAR();

        int rbuf = 0, sbuf = 2;
#pragma unroll 1
        for (int tk = 0; tk < ntiles; tk++) {
            const bf16* buf = &KVs[rbuf * 8192];
            if (tk + 2 < ntiles) {  // stage(t+2): drained at t+1's end (2 bodies away)
                bf16* nb = &KVs[sbuf * 8192 + tid * 8];
                gld_lds16(pK, nb);
                gld_lds16(pK2, nb + 2048);
                gld_lds16(pV, nb + 4096);
                gld_lds16(pV2, nb + 6144);
                pK += 64 * 1024; pK2 += 64 * 1024; pV += 64; pV2 += 64;
            }

            // S^T = K . Q^T for both strips; each kf read feeds 2 MFMAs
            f32x4 stA[4] = {}, stB[4] = {};
#pragma unroll
            for (int ks = 0; ks < 2; ks++)
#pragma unroll
                for (int j = 0; j < 4; j++) {
                    const bf16x8 kf =
                        *(const bf16x8*)&buf[(j * 16 + l16) * 64 + (ks ? cofB : cofA)];
                    stA[j] = MFMA16(kf, qfA[ks], stA[j]);
                    stB[j] = MFMA16(kf, qfB[ks], stB[j]);
                }

            // softmax per strip (A's diagonal at ntiles-2; B's at ntiles-1, where A is
            // fully masked via qrel-64 -> pfA = 0)
            bf16x8 pfA[2], pfB[2];
            if (tk < ntiles - 2) {
                softmax_reg<false>(stA, pfA, qrel);
                softmax_reg<false>(stB, pfB, qrel);
            } else if (tk == ntiles - 2) {
                softmax_reg<true>(stA, pfA, qrel);
                softmax_reg<false>(stB, pfB, qrel);
            } else {
                softmax_reg<true>(stA, pfA, qrel - 64);
                softmax_reg<true>(stB, pfB, qrel);
            }

            // l-sums via MFMA ones-fragment
            laccA = MFMA16(onesf, pfA[0], laccA);
            laccA = MFMA16(onesf, pfA[1], laccA);
            laccB = MFMA16(onesf, pfB[0], laccB);
            laccB = MFMA16(onesf, pfB[1], laccB);

            // O^T += V^T . P^T; each vf read feeds 2 MFMAs
#pragma unroll
            for (int ks = 0; ks < 2; ks++)
#pragma unroll
                for (int db = 0; db < 4; db++) {
                    const bf16x8 vf = *(const bf16x8*)&buf[4096 + (db * 16 + l16) * 64 +
                                                           (ks ? cofB : cofA)];
                    otA[db] = MFMA16(vf, pfA[ks], otA[db]);
                    otB[db] = MFMA16(vf, pfB[ks], otB[db]);
                }

            if (tk + 1 < ntiles) {
                if (tk + 2 < ntiles) VWAIT4();  // drain stage(t+1); stage(t+2) in flight
                else VWAIT0();                  // tail: drain the last stage
                PBAR();                         // publish t+1; buf[rbuf] readers done
            }
            rbuf = (rbuf == 2) ? 0 : rbuf + 1;
            sbuf = (sbuf == 2) ? 0 : sbuf + 1;
        }

        // epilogue: per strip, O^T regs -> transpose scratch in buf[(ntiles+1)%3]
        // (no pending gld_lds; its readers done). Strips sequential through the same
        // per-wave 16x72 region (same-wave LDS ops are in-order -> WAR safe).
        bf16* ep = &KVs[((ntiles + 1) % 3) * 8192 + wave * (16 * 72)];
        const int orow = lane >> 2, oc = (lane & 3) * 16;
        {
            const float inv = 1.f / laccA[0];
#pragma unroll
            for (int db = 0; db < 4; db++) {
                bf16x4 w = {(bf16)(otA[db][0] * inv), (bf16)(otA[db][1] * inv),
                            (bf16)(otA[db][2] * inv), (bf16)(otA[db][3] * inv)};
                *(bf16x4*)&ep[l16 * 72 + db * 16 + quad * 4] = w;
            }
            bf16* Obase =
                O + ((size_t)(b * 2048 + q0 + wave * 16 + orow)) * 1024 + h * 64 + oc;
            const bf16* src = &ep[orow * 72 + oc];
            *(bf16x8*)&Obase[0] = *(const bf16x8*)&src[0];
            *(bf16x8*)&Obase[8] = *(const bf16x8*)&src[8];
        }
        {
            const float inv = 1.f / laccB[0];
#pragma unroll
            for (int db = 0; db < 4; db++) {
                bf16x4 w = {(bf16)(otB[db][0] * inv), (bf16)(otB[db][1] * inv),
                            (bf16)(otB[db][2] * inv), (bf16)(otB[db][3] * inv)};
                *(bf16x4*)&ep[l16 * 72 + db * 16 + quad * 4] = w;
            }
            bf16* Obase =
                O + ((size_t)(b * 2048 + q0 + 64 + wave * 16 + orow)) * 1024 + h * 64 + oc;
            const bf16* src = &ep[orow * 72 + oc];
            *(bf16x8*)&Obase[0] = *(const bf16x8*)&src[0];
            *(bf16x8*)&Obase[8] = *(const bf16x8*)&src[8];
        }
        __syncthreads();  // all buffers drained + epilogue reads done before next phase
    }
}

extern "C" void kernel_launch(void* const* d_in, const int* in_sizes, int n_in,
                              void* d_out, int out_size, void* d_ws, size_t ws_size,
                              hipStream_t stream) {
    const float* x = (const float*)d_in[0];
    const float* Wq = (const float*)d_in[1];
    const float* bq = (const float*)d_in[2];
    const float* Wk = (const float*)d_in[3];
    const float* bk = (const float*)d_in[4];
    const float* Wv = (const float*)d_in[5];
    const float* bv = (const float*)d_in[6];
    float* out = (float*)d_out;

    const int M = 8192;  // B*T
    const size_t sz_x = (size_t)M * 1024;
    const size_t sz_w = (size_t)1024 * 1024;

    char* p = (char*)d_ws;
    bf16* xb = (bf16*)p;   p += sz_x * 2;
    bf16* Wcat = (bf16*)p; p += 3 * sz_w * 2;  // [Wq^T ; Wk^T ; Wv^T]
    bf16* qb = (bf16*)p;   p += sz_x * 2;
    bf16* kb = (bf16*)p;   p += sz_x * 2;
    bf16* Vt = (bf16*)p;   p += sz_x * 2;  // [B*H][64][2048]
    bf16* yatt = (bf16*)p; p += sz_x * 2;

    // W transpose + x convert in one launch
    prep<<<dim3(2816), dim3(256), 0, stream>>>(Wq, Wk, Wv, Wcat, x, xb);

    // fused QKV projection: [8192,1024] @ [1024,3072] -- 256x128/BK32, 3-buf depth-2
    gemm_main<0><<<dim3(768), dim3(512), 0, stream>>>(xb, Wcat, bq, bk, bv, qb, kb, Vt, 24);
    attn<<<dim3(512), dim3(256), 0, stream>>>(qb, kb, Vt, yatt);
    // output projection (reference reuses v_proj): BM=256, grid 256 (R6 config)
    gemm_main<1><<<dim3(256), dim3(512), 0, stream>>>(yatt, Wcat + 2 * sz_w, bv, bv, bv,
                                                      out, out, out, 8);
}